// Round 1
// baseline (2040.072 us; speedup 1.0000x reference)
//
#include <hip/hip_runtime.h>
#include <hip/hip_bf16.h>

#define BH 32
#define SQ 2048
#define DD 128
#define SCALE 0.08838834764831845f

typedef short bf16x8 __attribute__((ext_vector_type(8)));
typedef float f32x4 __attribute__((ext_vector_type(4)));

__device__ __forceinline__ unsigned short f2bf(float f) {
    unsigned u = __float_as_uint(f);
    u = u + 0x7FFFu + ((u >> 16) & 1u);   // round-to-nearest-even
    return (unsigned short)(u >> 16);
}
__device__ __forceinline__ float bf2f(unsigned short h) {
    return __uint_as_float(((unsigned)h) << 16);
}

// Detect mask element width: int32 {0,1} has all bytes at (off%4!=0) zero;
// bool/uint8 random 0/1 has nonzero bytes there (P[miss] = 2^-48).
// Deterministic for fixed inputs; values are 0/1 so LSB byte == value.
__device__ __forceinline__ int mask_byte_shift(const void* m) {
    const unsigned char* p = (const unsigned char*)m;
    int l = threadIdx.x & 63;
    unsigned char v = p[l];
    unsigned long long nz = __ballot(((l & 3) != 0) && (v != 0));
    return (nz != 0ull) ? 0 : 2;   // byte offset = idx << shift
}

// ---------------- pre-pass: Q,K f32 -> bf16 ----------------
__global__ void cvt_qk(const float* __restrict__ q, const float* __restrict__ k,
                       unsigned short* __restrict__ qb, unsigned short* __restrict__ kb) {
    const size_t n4 = (size_t)BH * SQ * DD / 4;   // float4 count per tensor
    size_t i = (size_t)blockIdx.x * blockDim.x + threadIdx.x;
    size_t stride = (size_t)gridDim.x * blockDim.x;
    for (; i < 2 * n4; i += stride) {
        const float4* src = (i < n4) ? (const float4*)q : (const float4*)k;
        unsigned short* dst = (i < n4) ? qb : kb;
        size_t j = (i < n4) ? i : i - n4;
        float4 v = src[j];
        ushort4 o;
        o.x = f2bf(v.x); o.y = f2bf(v.y); o.z = f2bf(v.z); o.w = f2bf(v.w);
        *(ushort4*)(dst + j * 4) = o;
    }
}

// ---------------- pre-pass: V -> V^T bf16  (VT[b][d][k]) ----------------
#define VT_LD 136   // LDS bounce row stride (elems); 272B = 17*16 keeps b128 aligned
__global__ void cvt_vt(const float* __restrict__ v, unsigned short* __restrict__ vt) {
    __shared__ unsigned short tile[128 * VT_LD];
    int b = blockIdx.x >> 4;
    int kt = blockIdx.x & 15;
    size_t vbase = ((size_t)b * SQ + (size_t)kt * 128) * DD;
    int t = threadIdx.x;   // 512
    for (int i = 0; i < 8; ++i) {
        size_t fi = (size_t)i * 2048 + (size_t)t * 4;   // f32 idx within 128x128 tile
        float4 val = *(const float4*)(v + vbase + fi);
        int kk = (int)(fi >> 7);
        int d0 = (int)(fi & 127);
        tile[(d0 + 0) * VT_LD + kk] = f2bf(val.x);
        tile[(d0 + 1) * VT_LD + kk] = f2bf(val.y);
        tile[(d0 + 2) * VT_LD + kk] = f2bf(val.z);
        tile[(d0 + 3) * VT_LD + kk] = f2bf(val.w);
    }
    __syncthreads();
    int d = t >> 2, ks = (t & 3) * 32;
    size_t obase = (size_t)b * (DD * SQ) + (size_t)d * SQ + (size_t)kt * 128 + ks;
    const unsigned short* row = tile + d * VT_LD + ks;
    #pragma unroll
    for (int j = 0; j < 4; ++j)
        *(int4*)(vt + obase + j * 8) = *(const int4*)(row + j * 8);
}

// ---------------- main fused attention ----------------
// grid 2048: blockIdx = qt*8 + bg ; block 512 thr = 8 waves.
// Block covers heads b = bg*4 .. bg*4+3, q rows q0..q0+7.
// wave w: wb = w>>1 (head), wk = w&1 (k-half / d-half).
__global__ __launch_bounds__(512, 2) void attn_main(
    const float* __restrict__ bias, const void* __restrict__ mask,
    const unsigned short* __restrict__ Qb, const unsigned short* __restrict__ Kb,
    const unsigned short* __restrict__ VT,
    float* __restrict__ outp, float* __restrict__ attnp) {
    extern __shared__ char lds[];
    unsigned short* Plds = (unsigned short*)lds;        // [32 rows][2048] bf16, swizzled, 128KB
    float* biasT = (float*)(lds + 131072);              // [8 q][128 k][4 b] f32, 16KB
    float* rowsum = (float*)(lds + 147456);             // [32]
    float* rowinv = (float*)(lds + 147584);             // [32]

    int qt = blockIdx.x >> 3, bg = blockIdx.x & 7;
    int q0 = qt * 8;
    int tid = threadIdx.x, lane = tid & 63, w = tid >> 6;
    int wb = w >> 1, wk = w & 1;
    int b = bg * 4 + wb;
    int mshift = mask_byte_shift(mask);
    const unsigned char* M = (const unsigned char*)mask;

    if (tid < 32) rowsum[tid] = 0.f;

    int l15 = lane & 15, lhi = lane >> 4;
    int qrow = lhi * 4;              // C-frag row group: 0,4,8,12
    bool act = qrow < 8;             // lanes 0..31 hold valid q rows
    int qc = l15 < 7 ? l15 : 7;      // clamped A-row (QB=8 padded to 16)

    // Q fragments (loop-invariant): lane holds Q[q0+qc][ds*32 + lhi*8 .. +7]
    size_t qkbase = (size_t)b * (SQ * DD);
    bf16x8 qf[4];
    #pragma unroll
    for (int ds = 0; ds < 4; ++ds)
        qf[ds] = *(const bf16x8*)(Qb + qkbase + (size_t)(q0 + qc) * DD + ds * 32 + lhi * 8);

    // bias prefetch (regs) for iter 0
    float4 pre0, pre1;
    {
        int p0 = tid, p1 = tid + 512;
        pre0 = *(const float4*)(bias + ((size_t)(q0 + (p0 >> 7)) * SQ + (p0 & 127)) * BH + bg * 4);
        pre1 = *(const float4*)(bias + ((size_t)(q0 + (p1 >> 7)) * SQ + (p1 & 127)) * BH + bg * 4);
    }

    float part[4] = {0.f, 0.f, 0.f, 0.f};

    #pragma unroll 1
    for (int it = 0; it < 16; ++it) {
        __syncthreads();                      // biasT readers done / rowsum init visible
        ((float4*)biasT)[tid] = pre0;
        ((float4*)biasT)[tid + 512] = pre1;
        __syncthreads();                      // biasT ready
        if (it + 1 < 16) {                    // prefetch next tile under compute
            int p0 = tid, p1 = tid + 512;
            pre0 = *(const float4*)(bias + ((size_t)(q0 + (p0 >> 7)) * SQ + (it + 1) * 128 + (p0 & 127)) * BH + bg * 4);
            pre1 = *(const float4*)(bias + ((size_t)(q0 + (p1 >> 7)) * SQ + (it + 1) * 128 + (p1 & 127)) * BH + bg * 4);
        }
        int kb0 = it * 128;
        #pragma unroll
        for (int kf = 0; kf < 4; ++kf) {
            f32x4 acc = {0.f, 0.f, 0.f, 0.f};
            int kl = wk * 64 + kf * 16 + l15;   // 0..127 within iter
            int KL = kb0 + kl;                  // global k
            #pragma unroll
            for (int ds = 0; ds < 4; ++ds) {
                bf16x8 kfr = *(const bf16x8*)(Kb + qkbase + (size_t)KL * DD + ds * 32 + lhi * 8);
                acc = __builtin_amdgcn_mfma_f32_16x16x32_bf16(qf[ds], kfr, acc, 0, 0, 0);
            }
            if (act) {
                #pragma unroll
                for (int r = 0; r < 4; ++r) {
                    int q = qrow + r;   // 0..7
                    float s = acc[r] * SCALE + biasT[(q * 128 + kl) * 4 + wb];
                    size_t midx = ((size_t)b * SQ + (q0 + q)) * SQ + KL;
                    bool msk = M[midx << mshift] != 0;
                    float pv = msk ? 0.f : __expf(s);
                    part[r] += pv;
                    int row = wb * 8 + q;
                    int byteoff = row * 4096 + ((KL * 2) ^ (q << 4));
                    *(unsigned short*)(lds + byteoff) = f2bf(pv);
                }
            }
        }
    }

    // row sums: reduce over the 16 lanes of each l15-group, then LDS atomics
    #pragma unroll
    for (int r = 0; r < 4; ++r) {
        float v = part[r];
        v += __shfl_xor(v, 1); v += __shfl_xor(v, 2);
        v += __shfl_xor(v, 4); v += __shfl_xor(v, 8);
        if (act && l15 == 0) atomicAdd(&rowsum[wb * 8 + qrow + r], v);
    }
    __syncthreads();
    if (tid < 32) rowinv[tid] = 1.0f / rowsum[tid];
    __syncthreads();

    // B1: write normalized attn, coalesced full rows
    #pragma unroll 1
    for (int rr = 0; rr < 32; ++rr) {
        int q = rr & 7, wbb = rr >> 3;
        int bb = bg * 4 + wbb;
        float inv = rowinv[rr];
        int byteoff = rr * 4096 + ((tid * 8) ^ (q << 4));
        ushort4 h = *(const ushort4*)(lds + byteoff);
        float4 o;
        o.x = bf2f(h.x) * inv; o.y = bf2f(h.y) * inv;
        o.z = bf2f(h.z) * inv; o.w = bf2f(h.w) * inv;
        *(float4*)(attnp + ((size_t)bb * SQ + q0 + q) * SQ + tid * 4) = o;
    }

    // B2: out = P @ V via MFMA; wave (wb, wk): rows wb, d-half wk
    f32x4 oacc[4] = {{0.f,0.f,0.f,0.f},{0.f,0.f,0.f,0.f},{0.f,0.f,0.f,0.f},{0.f,0.f,0.f,0.f}};
    int arow = wb * 8 + qc;
    size_t vtb = (size_t)b * (DD * SQ);
    #pragma unroll 2
    for (int ks = 0; ks < 64; ++ks) {
        int koff = ks * 32;
        bf16x8 af = *(const bf16x8*)(lds + arow * 4096 + (((koff + lhi * 8) * 2) ^ (qc << 4)));
        #pragma unroll
        for (int df = 0; df < 4; ++df) {
            int d = wk * 64 + df * 16 + l15;
            bf16x8 bfr = *(const bf16x8*)(VT + vtb + (size_t)d * SQ + koff + lhi * 8);
            oacc[df] = __builtin_amdgcn_mfma_f32_16x16x32_bf16(af, bfr, oacc[df], 0, 0, 0);
        }
    }
    if (act) {
        #pragma unroll
        for (int df = 0; df < 4; ++df) {
            #pragma unroll
            for (int r = 0; r < 4; ++r) {
                int q = qrow + r;
                outp[((size_t)b * SQ + q0 + q) * DD + wk * 64 + df * 16 + l15] =
                    oacc[df][r] * rowinv[wb * 8 + q];
            }
        }
    }
}

// ---------------- naive fallback (only if d_ws too small) ----------------
__global__ void attn_naive(const float* __restrict__ Q, const float* __restrict__ K,
                           const float* __restrict__ V, const float* __restrict__ bias,
                           const void* __restrict__ mask,
                           float* __restrict__ outp, float* __restrict__ attnp) {
    __shared__ float qrow[DD];
    __shared__ float prow[SQ];
    __shared__ float red[4];
    int b = blockIdx.x >> 11;
    int q = blockIdx.x & 2047;
    int tid = threadIdx.x;   // 256
    int mshift = mask_byte_shift(mask);
    const unsigned char* M = (const unsigned char*)mask;
    if (tid < DD) qrow[tid] = Q[((size_t)b * SQ + q) * DD + tid];
    __syncthreads();
    float lsum = 0.f;
    for (int k = tid; k < SQ; k += 256) {
        float s = 0.f;
        const float* kr = K + ((size_t)b * SQ + k) * DD;
        for (int d = 0; d < DD; ++d) s += qrow[d] * kr[d];
        s = s * SCALE + bias[((size_t)q * SQ + k) * BH + b];
        size_t midx = ((size_t)b * SQ + q) * SQ + k;
        float p = (M[midx << mshift] != 0) ? 0.f : __expf(s);
        prow[k] = p; lsum += p;
    }
    lsum += __shfl_xor(lsum, 1);  lsum += __shfl_xor(lsum, 2);
    lsum += __shfl_xor(lsum, 4);  lsum += __shfl_xor(lsum, 8);
    lsum += __shfl_xor(lsum, 16); lsum += __shfl_xor(lsum, 32);
    if ((tid & 63) == 0) red[tid >> 6] = lsum;
    __syncthreads();
    float inv = 1.0f / (red[0] + red[1] + red[2] + red[3]);
    for (int k = tid; k < SQ; k += 256) {
        float p = prow[k] * inv;
        prow[k] = p;
        attnp[((size_t)b * SQ + q) * SQ + k] = p;
    }
    __syncthreads();
    if (tid < DD) {
        float o = 0.f;
        for (int k = 0; k < SQ; ++k) o += prow[k] * V[((size_t)b * SQ + k) * DD + tid];
        outp[((size_t)b * SQ + q) * DD + tid] = o;
    }
}

extern "C" void kernel_launch(void* const* d_in, const int* in_sizes, int n_in,
                              void* d_out, int out_size, void* d_ws, size_t ws_size,
                              hipStream_t stream) {
    const float* Q = (const float*)d_in[0];
    const float* K = (const float*)d_in[1];
    const float* V = (const float*)d_in[2];
    const float* bias = (const float*)d_in[3];
    const void* mask = d_in[4];
    float* outp = (float*)d_out;
    float* attnp = outp + (size_t)BH * SQ * DD;

    const size_t tsz = (size_t)BH * SQ * DD;        // 8388608 elems
    const size_t need = tsz * 2 * 3;                // 48MB: Qbf, Kbf, VT
    if (ws_size >= need) {
        unsigned short* Qbf = (unsigned short*)d_ws;
        unsigned short* Kbf = Qbf + tsz;
        unsigned short* VTp = Kbf + tsz;
        cvt_qk<<<4096, 256, 0, stream>>>(Q, K, Qbf, Kbf);
        cvt_vt<<<512, 512, 0, stream>>>(V, VTp);
        hipFuncSetAttribute((const void*)attn_main,
                            hipFuncAttributeMaxDynamicSharedMemorySize, 147712);
        attn_main<<<2048, 512, 147712, stream>>>(bias, mask, Qbf, Kbf, VTp, outp, attnp);
    } else {
        attn_naive<<<BH * SQ, 256, 0, stream>>>(Q, K, V, bias, mask, outp, attnp);
    }
}

// Round 2
// 1230.560 us; speedup vs baseline: 1.6578x; 1.6578x over previous
//
#include <hip/hip_runtime.h>
#include <hip/hip_bf16.h>

#define BH 32
#define SQ 2048
#define DD 128
#define SCALE 0.08838834764831845f

typedef short bf16x8 __attribute__((ext_vector_type(8)));
typedef unsigned short us8 __attribute__((ext_vector_type(8)));
typedef float f32x4 __attribute__((ext_vector_type(4)));

__device__ __forceinline__ unsigned short f2bf(float f) {
    unsigned u = __float_as_uint(f);
    u = u + 0x7FFFu + ((u >> 16) & 1u);   // round-to-nearest-even
    return (unsigned short)(u >> 16);
}
__device__ __forceinline__ float bf2f(unsigned short h) {
    return __uint_as_float(((unsigned)h) << 16);
}

// Detect mask element width: int32 {0,1} has all bytes at (off%4!=0) zero;
// bool/uint8 random 0/1 has nonzero bytes there. Deterministic for fixed inputs.
__device__ __forceinline__ int mask_byte_shift(const void* m) {
    const unsigned char* p = (const unsigned char*)m;
    int l = threadIdx.x & 63;
    unsigned char v = p[l];
    unsigned long long nz = __ballot(((l & 3) != 0) && (v != 0));
    return (nz != 0ull) ? 0 : 2;   // byte offset = idx << shift
}

// ---------------- pre-pass: Q,K f32 -> bf16 ----------------
__global__ void cvt_qk(const float* __restrict__ q, const float* __restrict__ k,
                       unsigned short* __restrict__ qb, unsigned short* __restrict__ kb) {
    const size_t n4 = (size_t)BH * SQ * DD / 4;
    size_t i = (size_t)blockIdx.x * blockDim.x + threadIdx.x;
    size_t stride = (size_t)gridDim.x * blockDim.x;
    for (; i < 2 * n4; i += stride) {
        const float4* src = (i < n4) ? (const float4*)q : (const float4*)k;
        unsigned short* dst = (i < n4) ? qb : kb;
        size_t j = (i < n4) ? i : i - n4;
        float4 v = src[j];
        ushort4 o;
        o.x = f2bf(v.x); o.y = f2bf(v.y); o.z = f2bf(v.z); o.w = f2bf(v.w);
        *(ushort4*)(dst + j * 4) = o;
    }
}

// ---------------- pre-pass: V -> V^T bf16  (VT[b][d][k]) ----------------
#define VT_LD 136
__global__ void cvt_vt(const float* __restrict__ v, unsigned short* __restrict__ vt) {
    __shared__ unsigned short tile[128 * VT_LD];
    int b = blockIdx.x >> 4;
    int kt = blockIdx.x & 15;
    size_t vbase = ((size_t)b * SQ + (size_t)kt * 128) * DD;
    int t = threadIdx.x;   // 512
    for (int i = 0; i < 8; ++i) {
        size_t fi = (size_t)i * 2048 + (size_t)t * 4;
        float4 val = *(const float4*)(v + vbase + fi);
        int kk = (int)(fi >> 7);
        int d0 = (int)(fi & 127);
        tile[(d0 + 0) * VT_LD + kk] = f2bf(val.x);
        tile[(d0 + 1) * VT_LD + kk] = f2bf(val.y);
        tile[(d0 + 2) * VT_LD + kk] = f2bf(val.z);
        tile[(d0 + 3) * VT_LD + kk] = f2bf(val.w);
    }
    __syncthreads();
    int d = t >> 2, ks = (t & 3) * 32;
    size_t obase = (size_t)b * (DD * SQ) + (size_t)d * SQ + (size_t)kt * 128 + ks;
    const unsigned short* row = tile + d * VT_LD + ks;
    #pragma unroll
    for (int j = 0; j < 4; ++j)
        *(int4*)(vt + obase + j * 8) = *(const int4*)(row + j * 8);
}

// ---------------- pre-pass: biasT[b][q][k] = mask ? -1e18 : bias, bf16 ----------------
__global__ void xform_bias(const float* __restrict__ bias, const void* __restrict__ mask,
                           unsigned short* __restrict__ biasT) {
    __shared__ unsigned short T[32][520];
    int q = blockIdx.x >> 2, kc = blockIdx.x & 3;
    int k0 = kc * 512;
    int t = threadIdx.x;   // 256
    int mshift = mask_byte_shift(mask);
    const float4* src = (const float4*)(bias + ((size_t)q * SQ + k0) * BH);
    #pragma unroll
    for (int i = 0; i < 16; ++i) {
        int e4 = i * 256 + t;          // float4 idx within 64KB slab
        float4 v = src[e4];
        int elem = e4 * 4;
        int k = elem >> 5, b0 = elem & 31;
        T[b0 + 0][k] = f2bf(v.x); T[b0 + 1][k] = f2bf(v.y);
        T[b0 + 2][k] = f2bf(v.z); T[b0 + 3][k] = f2bf(v.w);
    }
    __syncthreads();
    const unsigned short NEGB = f2bf(-1e18f);
    int b = t >> 3;
    int toff = (t & 7) * 8;
    #pragma unroll
    for (int j = 0; j < 8; ++j) {
        int ks = j * 64 + toff;                       // 0..511, 8 elems per iter
        size_t gidx = ((size_t)b * SQ + q) * SQ + k0 + ks;
        unsigned short o[8];
        if (mshift == 2) {
            const int4* mp = (const int4*)((const int*)mask + gidx);
            int4 m0 = mp[0], m1 = mp[1];
            o[0] = m0.x ? NEGB : T[b][ks + 0];
            o[1] = m0.y ? NEGB : T[b][ks + 1];
            o[2] = m0.z ? NEGB : T[b][ks + 2];
            o[3] = m0.w ? NEGB : T[b][ks + 3];
            o[4] = m1.x ? NEGB : T[b][ks + 4];
            o[5] = m1.y ? NEGB : T[b][ks + 5];
            o[6] = m1.z ? NEGB : T[b][ks + 6];
            o[7] = m1.w ? NEGB : T[b][ks + 7];
        } else {
            uint2 mw = *(const uint2*)((const unsigned char*)mask + gidx);
            #pragma unroll
            for (int by = 0; by < 4; ++by) {
                o[by]     = ((mw.x >> (by * 8)) & 0xFF) ? NEGB : T[b][ks + by];
                o[4 + by] = ((mw.y >> (by * 8)) & 0xFF) ? NEGB : T[b][ks + 4 + by];
            }
        }
        us8 pk;
        #pragma unroll
        for (int c = 0; c < 8; ++c) pk[c] = o[c];
        *(us8*)(biasT + gidx) = pk;
    }
}

// ---------------- K_A: E = exp(QK^T*scale + biasT), row sums ----------------
// grid 2048: blockIdx = b*64 + qt. block 512 = 8 waves; wave w owns k in [w*256, w*256+256).
// Swapped mfma: A=K (M rows = k), B=Q (N cols = q) -> lane holds 4 consecutive k per q.
template<int EBF>
__global__ __launch_bounds__(512, 4) void attn_scores(
    const unsigned short* __restrict__ Qb, const unsigned short* __restrict__ Kb,
    const unsigned short* __restrict__ biasT, float* __restrict__ rowinvG,
    float* __restrict__ Ef, unsigned short* __restrict__ Ebf) {
    __shared__ float rs[32];
    int b = blockIdx.x >> 6, qt = blockIdx.x & 63;
    int q0 = qt * 32;
    int tid = threadIdx.x, lane = tid & 63, w = tid >> 6;
    int l15 = lane & 15, lhi = lane >> 4;
    if (tid < 32) rs[tid] = 0.f;
    __syncthreads();
    size_t headQK = (size_t)b * (SQ * DD);
    size_t ebase = (size_t)b * SQ * SQ;
    bf16x8 qf[2][4];
    #pragma unroll
    for (int qg = 0; qg < 2; ++qg)
        #pragma unroll
        for (int ds = 0; ds < 4; ++ds)
            qf[qg][ds] = *(const bf16x8*)(Qb + headQK +
                           (size_t)(q0 + qg * 16 + l15) * DD + ds * 32 + lhi * 8);
    float ps[2] = {0.f, 0.f};
    #pragma unroll 1
    for (int kt = 0; kt < 16; ++kt) {
        int kbase = w * 256 + kt * 16;
        bf16x8 kf[4];
        #pragma unroll
        for (int ds = 0; ds < 4; ++ds)
            kf[ds] = *(const bf16x8*)(Kb + headQK +
                       (size_t)(kbase + l15) * DD + ds * 32 + lhi * 8);
        #pragma unroll
        for (int qg = 0; qg < 2; ++qg) {
            f32x4 acc = {0.f, 0.f, 0.f, 0.f};
            #pragma unroll
            for (int ds = 0; ds < 4; ++ds)
                acc = __builtin_amdgcn_mfma_f32_16x16x32_bf16(kf[ds], qf[qg][ds], acc, 0, 0, 0);
            int q = q0 + qg * 16 + l15;
            int k = kbase + lhi * 4;
            size_t eidx = ebase + (size_t)q * SQ + k;
            ushort4 bv = *(const ushort4*)(biasT + eidx);
            float u0 = __expf(acc[0] * SCALE + bf2f(bv.x));
            float u1 = __expf(acc[1] * SCALE + bf2f(bv.y));
            float u2 = __expf(acc[2] * SCALE + bf2f(bv.z));
            float u3 = __expf(acc[3] * SCALE + bf2f(bv.w));
            ps[qg] += (u0 + u1) + (u2 + u3);
            if (EBF) {
                ushort4 st;
                st.x = f2bf(u0); st.y = f2bf(u1); st.z = f2bf(u2); st.w = f2bf(u3);
                *(ushort4*)(Ebf + eidx) = st;
            } else {
                float4 st = {u0, u1, u2, u3};
                *(float4*)(Ef + eidx) = st;
            }
        }
    }
    #pragma unroll
    for (int qg = 0; qg < 2; ++qg) {
        float v = ps[qg];
        v += __shfl_xor(v, 16);
        v += __shfl_xor(v, 32);
        if (lane < 16) atomicAdd(&rs[qg * 16 + l15], v);
    }
    __syncthreads();
    if (tid < 32) rowinvG[(size_t)b * SQ + q0 + tid] = 1.0f / rs[tid];
}

// ---------------- K_B: out = (E/rowsum) @ V ; attn = E/rowsum ----------------
// grid 2048: blockIdx = b*64 + qt. 8 waves: w = qg*4 + ds (qg: 16-q group, ds: 32-d slice)
template<int EBF>
__global__ __launch_bounds__(512, 4) void attn_pv(
    const unsigned short* __restrict__ VT, const float* __restrict__ rowinvG,
    float* __restrict__ Ef, const unsigned short* __restrict__ Ebf,
    float* __restrict__ outp, float* __restrict__ attnp) {
    int b = blockIdx.x >> 6, qt = blockIdx.x & 63;
    int q0 = qt * 32;
    int tid = threadIdx.x, lane = tid & 63, w = tid >> 6;
    int qg = w >> 2, ds = w & 3;
    int l15 = lane & 15, lhi = lane >> 4;
    size_t ebase = (size_t)b * SQ * SQ;
    size_t vbase = (size_t)b * (DD * SQ);
    f32x4 acc[2] = {{0.f,0.f,0.f,0.f},{0.f,0.f,0.f,0.f}};
    const size_t arow = ebase + (size_t)(q0 + qg * 16 + l15) * SQ;
    #pragma unroll 2
    for (int kt = 0; kt < 64; ++kt) {
        int k = kt * 32 + lhi * 8;
        bf16x8 af;
        if (EBF) {
            af = *(const bf16x8*)(Ebf + arow + k);
        } else {
            float4 a0 = *(const float4*)(Ef + arow + k);
            float4 a1 = *(const float4*)(Ef + arow + k + 4);
            af[0] = (short)f2bf(a0.x); af[1] = (short)f2bf(a0.y);
            af[2] = (short)f2bf(a0.z); af[3] = (short)f2bf(a0.w);
            af[4] = (short)f2bf(a1.x); af[5] = (short)f2bf(a1.y);
            af[6] = (short)f2bf(a1.z); af[7] = (short)f2bf(a1.w);
        }
        #pragma unroll
        for (int m = 0; m < 2; ++m) {
            bf16x8 bfr = *(const bf16x8*)(VT + vbase +
                           (size_t)(ds * 32 + m * 16 + l15) * SQ + k);
            acc[m] = __builtin_amdgcn_mfma_f32_16x16x32_bf16(af, bfr, acc[m], 0, 0, 0);
        }
    }
    #pragma unroll
    for (int m = 0; m < 2; ++m)
        #pragma unroll
        for (int r = 0; r < 4; ++r) {
            int q = q0 + qg * 16 + lhi * 4 + r;
            float inv = rowinvG[(size_t)b * SQ + q];
            outp[((size_t)b * SQ + q) * DD + ds * 32 + m * 16 + l15] = acc[m][r] * inv;
        }
    if (EBF == 0) __syncthreads();   // all E reads complete before in-place overwrite
    int row = tid >> 4;              // 0..31
    int coff = (tid & 15) * 4;
    float inv = rowinvG[(size_t)b * SQ + q0 + row];
    size_t rbase = ebase + (size_t)(q0 + row) * SQ;
    #pragma unroll 4
    for (int it = 0; it < 32; ++it) {
        int k = it * 64 + coff;
        if (EBF) {
            ushort4 e = *(const ushort4*)(Ebf + rbase + k);
            float4 o;
            o.x = bf2f(e.x) * inv; o.y = bf2f(e.y) * inv;
            o.z = bf2f(e.z) * inv; o.w = bf2f(e.w) * inv;
            *(float4*)(attnp + rbase + k) = o;
        } else {
            float4 u = *(const float4*)(Ef + rbase + k);
            u.x *= inv; u.y *= inv; u.z *= inv; u.w *= inv;
            *(float4*)(attnp + rbase + k) = u;
        }
    }
}

// ---------------- fallback: round-0 fused kernel (ws >= 48MB) ----------------
__global__ __launch_bounds__(512, 2) void attn_main(
    const float* __restrict__ bias, const void* __restrict__ mask,
    const unsigned short* __restrict__ Qb, const unsigned short* __restrict__ Kb,
    const unsigned short* __restrict__ VT,
    float* __restrict__ outp, float* __restrict__ attnp) {
    extern __shared__ char lds[];
    float* biasT = (float*)(lds + 131072);
    float* rowsum = (float*)(lds + 147456);
    float* rowinv = (float*)(lds + 147584);
    int qt = blockIdx.x >> 3, bg = blockIdx.x & 7;
    int q0 = qt * 8;
    int tid = threadIdx.x, lane = tid & 63, w = tid >> 6;
    int wb = w >> 1, wk = w & 1;
    int b = bg * 4 + wb;
    int mshift = mask_byte_shift(mask);
    const unsigned char* M = (const unsigned char*)mask;
    if (tid < 32) rowsum[tid] = 0.f;
    int l15 = lane & 15, lhi = lane >> 4;
    int qrow = lhi * 4;
    bool act = qrow < 8;
    int qc = l15 < 7 ? l15 : 7;
    size_t qkbase = (size_t)b * (SQ * DD);
    bf16x8 qf[4];
    #pragma unroll
    for (int ds = 0; ds < 4; ++ds)
        qf[ds] = *(const bf16x8*)(Qb + qkbase + (size_t)(q0 + qc) * DD + ds * 32 + lhi * 8);
    float4 pre0, pre1;
    {
        int p0 = tid, p1 = tid + 512;
        pre0 = *(const float4*)(bias + ((size_t)(q0 + (p0 >> 7)) * SQ + (p0 & 127)) * BH + bg * 4);
        pre1 = *(const float4*)(bias + ((size_t)(q0 + (p1 >> 7)) * SQ + (p1 & 127)) * BH + bg * 4);
    }
    float part[4] = {0.f, 0.f, 0.f, 0.f};
    #pragma unroll 1
    for (int it = 0; it < 16; ++it) {
        __syncthreads();
        ((float4*)biasT)[tid] = pre0;
        ((float4*)biasT)[tid + 512] = pre1;
        __syncthreads();
        if (it + 1 < 16) {
            int p0 = tid, p1 = tid + 512;
            pre0 = *(const float4*)(bias + ((size_t)(q0 + (p0 >> 7)) * SQ + (it + 1) * 128 + (p0 & 127)) * BH + bg * 4);
            pre1 = *(const float4*)(bias + ((size_t)(q0 + (p1 >> 7)) * SQ + (it + 1) * 128 + (p1 & 127)) * BH + bg * 4);
        }
        int kb0 = it * 128;
        #pragma unroll
        for (int kf = 0; kf < 4; ++kf) {
            f32x4 acc = {0.f, 0.f, 0.f, 0.f};
            int kl = wk * 64 + kf * 16 + l15;
            int KL = kb0 + kl;
            #pragma unroll
            for (int ds = 0; ds < 4; ++ds) {
                bf16x8 kfr = *(const bf16x8*)(Kb + qkbase + (size_t)KL * DD + ds * 32 + lhi * 8);
                acc = __builtin_amdgcn_mfma_f32_16x16x32_bf16(qf[ds], kfr, acc, 0, 0, 0);
            }
            if (act) {
                #pragma unroll
                for (int r = 0; r < 4; ++r) {
                    int q = qrow + r;
                    float s = acc[r] * SCALE + biasT[(q * 128 + kl) * 4 + wb];
                    size_t midx = ((size_t)b * SQ + (q0 + q)) * SQ + KL;
                    bool msk = M[midx << mshift] != 0;
                    float pv = msk ? 0.f : __expf(s);
                    part[r] += pv;
                    int row = wb * 8 + q;
                    int byteoff = row * 4096 + ((KL * 2) ^ (q << 4));
                    *(unsigned short*)(lds + byteoff) = f2bf(pv);
                }
            }
        }
    }
    #pragma unroll
    for (int r = 0; r < 4; ++r) {
        float v = part[r];
        v += __shfl_xor(v, 1); v += __shfl_xor(v, 2);
        v += __shfl_xor(v, 4); v += __shfl_xor(v, 8);
        if (act && l15 == 0) atomicAdd(&rowsum[wb * 8 + qrow + r], v);
    }
    __syncthreads();
    if (tid < 32) rowinv[tid] = 1.0f / rowsum[tid];
    __syncthreads();
    #pragma unroll 1
    for (int rr = 0; rr < 32; ++rr) {
        int q = rr & 7, wbb = rr >> 3;
        int bb = bg * 4 + wbb;
        float inv = rowinv[rr];
        int byteoff = rr * 4096 + ((tid * 8) ^ (q << 4));
        ushort4 h = *(const ushort4*)(lds + byteoff);
        float4 o;
        o.x = bf2f(h.x) * inv; o.y = bf2f(h.y) * inv;
        o.z = bf2f(h.z) * inv; o.w = bf2f(h.w) * inv;
        *(float4*)(attnp + ((size_t)bb * SQ + q0 + q) * SQ + tid * 4) = o;
    }
    f32x4 oacc[4] = {{0.f,0.f,0.f,0.f},{0.f,0.f,0.f,0.f},{0.f,0.f,0.f,0.f},{0.f,0.f,0.f,0.f}};
    int arow = wb * 8 + qc;
    size_t vtb = (size_t)b * (DD * SQ);
    #pragma unroll 2
    for (int ks = 0; ks < 64; ++ks) {
        int koff = ks * 32;
        bf16x8 af = *(const bf16x8*)(lds + arow * 4096 + (((koff + lhi * 8) * 2) ^ (qc << 4)));
        #pragma unroll
        for (int df = 0; df < 4; ++df) {
            int d = wk * 64 + df * 16 + l15;
            bf16x8 bfr = *(const bf16x8*)(VT + vtb + (size_t)d * SQ + koff + lhi * 8);
            oacc[df] = __builtin_amdgcn_mfma_f32_16x16x32_bf16(af, bfr, oacc[df], 0, 0, 0);
        }
    }
    if (act) {
        #pragma unroll
        for (int df = 0; df < 4; ++df)
            #pragma unroll
            for (int r = 0; r < 4; ++r) {
                int q = qrow + r;
                outp[((size_t)b * SQ + q0 + q) * DD + wk * 64 + df * 16 + l15] =
                    oacc[df][r] * rowinv[wb * 8 + q];
            }
    }
}

// ---------------- naive last-resort ----------------
__global__ void attn_naive(const float* __restrict__ Q, const float* __restrict__ K,
                           const float* __restrict__ V, const float* __restrict__ bias,
                           const void* __restrict__ mask,
                           float* __restrict__ outp, float* __restrict__ attnp) {
    __shared__ float qrow[DD];
    __shared__ float prow[SQ];
    __shared__ float red[4];
    int b = blockIdx.x >> 11;
    int q = blockIdx.x & 2047;
    int tid = threadIdx.x;
    int mshift = mask_byte_shift(mask);
    const unsigned char* M = (const unsigned char*)mask;
    if (tid < DD) qrow[tid] = Q[((size_t)b * SQ + q) * DD + tid];
    __syncthreads();
    float lsum = 0.f;
    for (int k = tid; k < SQ; k += 256) {
        float s = 0.f;
        const float* kr = K + ((size_t)b * SQ + k) * DD;
        for (int d = 0; d < DD; ++d) s += qrow[d] * kr[d];
        s = s * SCALE + bias[((size_t)q * SQ + k) * BH + b];
        size_t midx = ((size_t)b * SQ + q) * SQ + k;
        float p = (M[midx << mshift] != 0) ? 0.f : __expf(s);
        prow[k] = p; lsum += p;
    }
    lsum += __shfl_xor(lsum, 1);  lsum += __shfl_xor(lsum, 2);
    lsum += __shfl_xor(lsum, 4);  lsum += __shfl_xor(lsum, 8);
    lsum += __shfl_xor(lsum, 16); lsum += __shfl_xor(lsum, 32);
    if ((tid & 63) == 0) red[tid >> 6] = lsum;
    __syncthreads();
    float inv = 1.0f / (red[0] + red[1] + red[2] + red[3]);
    for (int k = tid; k < SQ; k += 256) {
        float p = prow[k] * inv;
        prow[k] = p;
        attnp[((size_t)b * SQ + q) * SQ + k] = p;
    }
    __syncthreads();
    if (tid < DD) {
        float o = 0.f;
        for (int k = 0; k < SQ; ++k) o += prow[k] * V[((size_t)b * SQ + k) * DD + tid];
        outp[((size_t)b * SQ + q) * DD + tid] = o;
    }
}

extern "C" void kernel_launch(void* const* d_in, const int* in_sizes, int n_in,
                              void* d_out, int out_size, void* d_ws, size_t ws_size,
                              hipStream_t stream) {
    const float* Q = (const float*)d_in[0];
    const float* K = (const float*)d_in[1];
    const float* V = (const float*)d_in[2];
    const float* bias = (const float*)d_in[3];
    const void* mask = d_in[4];
    float* outp = (float*)d_out;
    float* attnp = outp + (size_t)BH * SQ * DD;

    const size_t tsz = (size_t)BH * SQ * DD;          // 8388608
    const size_t biasN = (size_t)BH * SQ * SQ;        // 134217728
    const size_t cvtB = tsz * 2 * 3;                  // 48 MB
    const size_t needF32 = cvtB + biasN * 2 + (size_t)BH * SQ * 4;   // ~319 MB
    const size_t needBF = needF32 + biasN * 2;                        // ~587 MB

    if (ws_size >= needF32) {
        char* p = (char*)d_ws;
        unsigned short* Qbf = (unsigned short*)p;          p += tsz * 2;
        unsigned short* Kbf = (unsigned short*)p;          p += tsz * 2;
        unsigned short* VTp = (unsigned short*)p;          p += tsz * 2;
        unsigned short* biasT = (unsigned short*)p;        p += biasN * 2;
        float* rowinvG = (float*)p;                        p += (size_t)BH * SQ * 4;
        unsigned short* Ebf = (unsigned short*)p;          // only valid if needBF fits

        cvt_qk<<<4096, 256, 0, stream>>>(Q, K, Qbf, Kbf);
        cvt_vt<<<512, 512, 0, stream>>>(V, VTp);
        xform_bias<<<8192, 256, 0, stream>>>(bias, mask, biasT);
        if (ws_size >= needBF) {
            attn_scores<1><<<2048, 512, 0, stream>>>(Qbf, Kbf, biasT, rowinvG, attnp, Ebf);
            attn_pv<1><<<2048, 512, 0, stream>>>(VTp, rowinvG, attnp, Ebf, outp, attnp);
        } else {
            attn_scores<0><<<2048, 512, 0, stream>>>(Qbf, Kbf, biasT, rowinvG, attnp, nullptr);
            attn_pv<0><<<2048, 512, 0, stream>>>(VTp, rowinvG, attnp, nullptr, outp, attnp);
        }
    } else if (ws_size >= cvtB) {
        unsigned short* Qbf = (unsigned short*)d_ws;
        unsigned short* Kbf = Qbf + tsz;
        unsigned short* VTp = Kbf + tsz;
        cvt_qk<<<4096, 256, 0, stream>>>(Q, K, Qbf, Kbf);
        cvt_vt<<<512, 512, 0, stream>>>(V, VTp);
        hipFuncSetAttribute((const void*)attn_main,
                            hipFuncAttributeMaxDynamicSharedMemorySize, 147712);
        attn_main<<<2048, 512, 147712, stream>>>(bias, mask, Qbf, Kbf, VTp, outp, attnp);
    } else {
        attn_naive<<<BH * SQ, 256, 0, stream>>>(Q, K, V, bias, mask, outp, attnp);
    }
}

// Round 3
// 782.962 us; speedup vs baseline: 2.6056x; 1.5717x over previous
//
#include <hip/hip_runtime.h>
#include <hip/hip_bf16.h>

#define BH 32
#define SQ 2048
#define DD 128
#define SCALE 0.08838834764831845f

typedef short bf16x8 __attribute__((ext_vector_type(8)));
typedef unsigned short us8 __attribute__((ext_vector_type(8)));
typedef float f32x4 __attribute__((ext_vector_type(4)));

typedef __attribute__((address_space(1))) const unsigned gu32;
typedef __attribute__((address_space(3))) unsigned lu32;
__device__ __forceinline__ void gll16(const void* g, void* l) {
    __builtin_amdgcn_global_load_lds((gu32*)g, (lu32*)l, 16, 0, 0);
}

__device__ __forceinline__ unsigned short f2bf(float f) {
    unsigned u = __float_as_uint(f);
    u = u + 0x7FFFu + ((u >> 16) & 1u);   // RNE
    return (unsigned short)(u >> 16);
}
__device__ __forceinline__ float bf2f(unsigned short h) {
    return __uint_as_float(((unsigned)h) << 16);
}

// mask elem width detect: int32 {0,1} has zero bytes at off%4!=0
__device__ __forceinline__ int mask_byte_shift(const void* m) {
    const unsigned char* p = (const unsigned char*)m;
    int l = threadIdx.x & 63;
    unsigned char v = p[l];
    unsigned long long nz = __ballot(((l & 3) != 0) && (v != 0));
    return (nz != 0ull) ? 0 : 2;
}

// ---------------- pre-pass: Q,K f32 -> bf16 ----------------
__global__ void cvt_qk(const float* __restrict__ q, const float* __restrict__ k,
                       unsigned short* __restrict__ qb, unsigned short* __restrict__ kb) {
    const size_t n4 = (size_t)BH * SQ * DD / 4;
    size_t i = (size_t)blockIdx.x * blockDim.x + threadIdx.x;
    size_t stride = (size_t)gridDim.x * blockDim.x;
    for (; i < 2 * n4; i += stride) {
        const float4* src = (i < n4) ? (const float4*)q : (const float4*)k;
        unsigned short* dst = (i < n4) ? qb : kb;
        size_t j = (i < n4) ? i : i - n4;
        float4 v = src[j];
        ushort4 o;
        o.x = f2bf(v.x); o.y = f2bf(v.y); o.z = f2bf(v.z); o.w = f2bf(v.w);
        *(ushort4*)(dst + j * 4) = o;
    }
}

// ---------------- pre-pass: V -> V^T bf16 (VT[b][d][k]) ----------------
#define VT_LD 136
__global__ void cvt_vt(const float* __restrict__ v, unsigned short* __restrict__ vt) {
    __shared__ unsigned short tile[128 * VT_LD];
    int b = blockIdx.x >> 4;
    int kt = blockIdx.x & 15;
    size_t vbase = ((size_t)b * SQ + (size_t)kt * 128) * DD;
    int t = threadIdx.x;   // 512
    for (int i = 0; i < 8; ++i) {
        size_t fi = (size_t)i * 2048 + (size_t)t * 4;
        float4 val = *(const float4*)(v + vbase + fi);
        int kk = (int)(fi >> 7);
        int d0 = (int)(fi & 127);
        tile[(d0 + 0) * VT_LD + kk] = f2bf(val.x);
        tile[(d0 + 1) * VT_LD + kk] = f2bf(val.y);
        tile[(d0 + 2) * VT_LD + kk] = f2bf(val.z);
        tile[(d0 + 3) * VT_LD + kk] = f2bf(val.w);
    }
    __syncthreads();
    int d = t >> 2, ks = (t & 3) * 32;
    size_t obase = (size_t)b * (DD * SQ) + (size_t)d * SQ + (size_t)kt * 128 + ks;
    const unsigned short* row = tile + d * VT_LD + ks;
    #pragma unroll
    for (int j = 0; j < 4; ++j)
        *(int4*)(vt + obase + j * 8) = *(const int4*)(row + j * 8);
}

// ---------------- pre-pass: biasT[b][q][k] = mask ? -1e18 : bias (bf16) ----------------
__global__ void xform_bias(const float* __restrict__ bias, const void* __restrict__ mask,
                           unsigned short* __restrict__ biasT) {
    __shared__ unsigned short T[32][520];
    int q = blockIdx.x >> 2, kc = blockIdx.x & 3;
    int k0 = kc * 512;
    int t = threadIdx.x;   // 256
    int mshift = mask_byte_shift(mask);
    const float4* src = (const float4*)(bias + ((size_t)q * SQ + k0) * BH);
    #pragma unroll
    for (int i = 0; i < 16; ++i) {
        int e4 = i * 256 + t;
        float4 v = src[e4];
        int elem = e4 * 4;
        int k = elem >> 5, b0 = elem & 31;
        T[b0 + 0][k] = f2bf(v.x); T[b0 + 1][k] = f2bf(v.y);
        T[b0 + 2][k] = f2bf(v.z); T[b0 + 3][k] = f2bf(v.w);
    }
    __syncthreads();
    const unsigned short NEGB = f2bf(-1e18f);
    int b = t >> 3;
    int toff = (t & 7) * 8;
    #pragma unroll
    for (int j = 0; j < 8; ++j) {
        int ks = j * 64 + toff;
        size_t gidx = ((size_t)b * SQ + q) * SQ + k0 + ks;
        unsigned short o[8];
        if (mshift == 2) {
            const int4* mp = (const int4*)((const int*)mask + gidx);
            int4 m0 = mp[0], m1 = mp[1];
            o[0] = m0.x ? NEGB : T[b][ks + 0];
            o[1] = m0.y ? NEGB : T[b][ks + 1];
            o[2] = m0.z ? NEGB : T[b][ks + 2];
            o[3] = m0.w ? NEGB : T[b][ks + 3];
            o[4] = m1.x ? NEGB : T[b][ks + 4];
            o[5] = m1.y ? NEGB : T[b][ks + 5];
            o[6] = m1.z ? NEGB : T[b][ks + 6];
            o[7] = m1.w ? NEGB : T[b][ks + 7];
        } else {
            uint2 mw = *(const uint2*)((const unsigned char*)mask + gidx);
            #pragma unroll
            for (int by = 0; by < 4; ++by) {
                o[by]     = ((mw.x >> (by * 8)) & 0xFF) ? NEGB : T[b][ks + by];
                o[4 + by] = ((mw.y >> (by * 8)) & 0xFF) ? NEGB : T[b][ks + 4 + by];
            }
        }
        us8 pk;
        #pragma unroll
        for (int c = 0; c < 8; ++c) pk[c] = o[c];
        *(us8*)(biasT + gidx) = pk;
    }
}

// ---------------- K_A: E = exp(QK^T*scale + biasT) bf16, rowinv ----------------
// grid 2048. XCD swizzle: xcd=bid&7, head = xcd*4 + (slot>>6), qt = slot&63.
// block = (head, 32 q rows) x full k. 8 waves; wave w owns k-rows [w*16, w*16+16)
// within each 128-k step. A=K (M=k), B=Q (N=q). K staged via global_load_lds,
// double-buffered 2x32KB, source pre-swizzled (col ^= (row&7)<<4).
__global__ __launch_bounds__(512, 4) void attn_scores(
    const unsigned short* __restrict__ Qb, const unsigned short* __restrict__ Kb,
    const unsigned short* __restrict__ biasT, float* __restrict__ rowinvG,
    unsigned short* __restrict__ Ebf) {
    extern __shared__ char smem[];   // 2 x 32768
    __shared__ float rs[32];
    int bid = blockIdx.x;
    int xcd = bid & 7, slot = bid >> 3;
    int b = xcd * 4 + (slot >> 6);
    int q0 = (slot & 63) * 32;
    int tid = threadIdx.x, lane = tid & 63, w = tid >> 6;
    int l15 = lane & 15, lhi = lane >> 4;

    const char* Kh = (const char*)(Kb + (size_t)b * SQ * DD);
    size_t qhead = (size_t)b * SQ * DD;
    size_t ehead = (size_t)b * SQ * SQ;

    if (tid < 32) rs[tid] = 0.f;

    // Q fragments in registers (loop-invariant)
    bf16x8 qf[2][4];
    #pragma unroll
    for (int qg = 0; qg < 2; ++qg)
        #pragma unroll
        for (int kk = 0; kk < 4; ++kk)
            qf[qg][kk] = *(const bf16x8*)(Qb + qhead +
                           (size_t)(q0 + qg * 16 + l15) * DD + kk * 32 + lhi * 8);

    // staging: K rows [s*128, s*128+128) x 128 d, 32KB, 4 gll/thread
    int srow = tid >> 4;                 // +32 per pass
    int scolb = (tid & 15) * 16;
    #pragma unroll
    for (int p = 0; p < 4; ++p) {
        int row = p * 32 + srow;
        gll16(Kh + (size_t)row * 256 + (scolb ^ ((row & 7) << 4)),
              smem + p * 8192 + tid * 16);
    }
    __syncthreads();

    float ps[2] = {0.f, 0.f};
    int kr = w * 16 + l15;               // k-row within step (LDS row)
    #pragma unroll 1
    for (int s = 0; s < 16; ++s) {
        int cur = s & 1;
        if (s < 15) {
            const char* base = Kh + (size_t)(s + 1) * 128 * 256;
            #pragma unroll
            for (int p = 0; p < 4; ++p) {
                int row = p * 32 + srow;
                gll16(base + (size_t)row * 256 + (scolb ^ ((row & 7) << 4)),
                      smem + (cur ^ 1) * 32768 + p * 8192 + tid * 16);
            }
        }
        // bias loads issued early (k = s*128 + w*16 + lhi*4)
        int kg = s * 128 + w * 16 + lhi * 4;
        ushort4 bv[2];
        #pragma unroll
        for (int qg = 0; qg < 2; ++qg)
            bv[qg] = *(const ushort4*)(biasT + ehead +
                        (size_t)(q0 + qg * 16 + l15) * SQ + kg);
        // A fragments from LDS
        bf16x8 akk[4];
        #pragma unroll
        for (int kk = 0; kk < 4; ++kk)
            akk[kk] = *(const bf16x8*)(smem + cur * 32768 + kr * 256 +
                         ((kk * 64 + lhi * 16) ^ ((kr & 7) << 4)));
        #pragma unroll
        for (int qg = 0; qg < 2; ++qg) {
            f32x4 acc = {0.f, 0.f, 0.f, 0.f};
            #pragma unroll
            for (int kk = 0; kk < 4; ++kk)
                acc = __builtin_amdgcn_mfma_f32_16x16x32_bf16(akk[kk], qf[qg][kk], acc, 0, 0, 0);
            float u0 = __expf(acc[0] * SCALE + bf2f(bv[qg].x));
            float u1 = __expf(acc[1] * SCALE + bf2f(bv[qg].y));
            float u2 = __expf(acc[2] * SCALE + bf2f(bv[qg].z));
            float u3 = __expf(acc[3] * SCALE + bf2f(bv[qg].w));
            ps[qg] += (u0 + u1) + (u2 + u3);
            ushort4 st;
            st.x = f2bf(u0); st.y = f2bf(u1); st.z = f2bf(u2); st.w = f2bf(u3);
            *(ushort4*)(Ebf + ehead + (size_t)(q0 + qg * 16 + l15) * SQ + kg) = st;
        }
        __syncthreads();
    }
    // rowsum: lanes with same l15 share q; reduce lhi then cross-wave
    #pragma unroll
    for (int qg = 0; qg < 2; ++qg) {
        float v = ps[qg];
        v += __shfl_xor(v, 16);
        v += __shfl_xor(v, 32);
        if (lane < 16) atomicAdd(&rs[qg * 16 + l15], v);
    }
    __syncthreads();
    if (tid < 32) rowinvG[(size_t)b * SQ + q0 + tid] = 1.0f / rs[tid];
}

// ---------------- K_B: out = (E @ V^T) * rowinv  (pure GEMM) ----------------
// grid 512: xcd=bid&7, head = xcd*4 + (slot>>4), qt = slot&15 (128 q rows).
// BK=64; A=E[128x64], B=VT[128x64] staged 16KB each, double-buffered (64KB).
// 8 waves = 2(m) x 4(n); wave tile 64q x 32d; 16 MFMA/iter.
__global__ __launch_bounds__(512, 4) void attn_pv(
    const unsigned short* __restrict__ Ebf, const unsigned short* __restrict__ VT,
    const float* __restrict__ rowinvG, float* __restrict__ outp) {
    extern __shared__ char smem[];   // 2 x (16384 A + 16384 B)
    int bid = blockIdx.x;
    int xcd = bid & 7, slot = bid >> 3;
    int b = xcd * 4 + (slot >> 4);
    int q0 = (slot & 15) * 128;
    int tid = threadIdx.x, lane = tid & 63, w = tid >> 6;
    int wm = w >> 2, wn = w & 3;
    int l15 = lane & 15, lhi = lane >> 4;

    const char* Eh = (const char*)Ebf + ((size_t)b * SQ + q0) * SQ * 2;
    const char* Vh = (const char*)VT + (size_t)b * DD * SQ * 2;

    int srow = tid >> 3;                 // 0..63, +64 per pass
    int scolb = (tid & 7) * 16;          // 0..112

    // prologue stage kt=0
    #pragma unroll
    for (int p = 0; p < 2; ++p) {
        int row = p * 64 + srow;
        int sw = scolb ^ ((row & 7) << 4);
        gll16(Eh + (size_t)row * 4096 + sw, smem + p * 8192 + tid * 16);
        gll16(Vh + (size_t)row * 4096 + sw, smem + 16384 + p * 8192 + tid * 16);
    }
    __syncthreads();

    f32x4 acc[4][2] = {};
    #pragma unroll 1
    for (int kt = 0; kt < 32; ++kt) {
        int cur = kt & 1;
        if (kt < 31) {
            size_t koff = (size_t)(kt + 1) * 128;
            char* dst = smem + (cur ^ 1) * 32768;
            #pragma unroll
            for (int p = 0; p < 2; ++p) {
                int row = p * 64 + srow;
                int sw = scolb ^ ((row & 7) << 4);
                gll16(Eh + (size_t)row * 4096 + koff + sw, dst + p * 8192 + tid * 16);
                gll16(Vh + (size_t)row * 4096 + koff + sw, dst + 16384 + p * 8192 + tid * 16);
            }
        }
        const char* Ab = smem + cur * 32768;
        const char* Bb = Ab + 16384;
        bf16x8 af[4][2], bf[2][2];
        #pragma unroll
        for (int m = 0; m < 4; ++m) {
            int qr = wm * 64 + m * 16 + l15;
            #pragma unroll
            for (int ks = 0; ks < 2; ++ks)
                af[m][ks] = *(const bf16x8*)(Ab + qr * 128 +
                              ((ks * 64 + lhi * 16) ^ ((qr & 7) << 4)));
        }
        #pragma unroll
        for (int n = 0; n < 2; ++n) {
            int dr = wn * 32 + n * 16 + l15;
            #pragma unroll
            for (int ks = 0; ks < 2; ++ks)
                bf[n][ks] = *(const bf16x8*)(Bb + dr * 128 +
                              ((ks * 64 + lhi * 16) ^ ((dr & 7) << 4)));
        }
        #pragma unroll
        for (int m = 0; m < 4; ++m)
            #pragma unroll
            for (int n = 0; n < 2; ++n)
                #pragma unroll
                for (int ks = 0; ks < 2; ++ks)
                    acc[m][n] = __builtin_amdgcn_mfma_f32_16x16x32_bf16(
                                  af[m][ks], bf[n][ks], acc[m][n], 0, 0, 0);
        __syncthreads();
    }
    #pragma unroll
    for (int m = 0; m < 4; ++m) {
        #pragma unroll
        for (int r = 0; r < 4; ++r) {
            int q = q0 + wm * 64 + m * 16 + lhi * 4 + r;
            float inv = rowinvG[(size_t)b * SQ + q];
            #pragma unroll
            for (int n = 0; n < 2; ++n)
                outp[((size_t)b * SQ + q) * DD + wn * 32 + n * 16 + l15] =
                    acc[m][n][r] * inv;
        }
    }
}

// ---------------- K_C: attn = Ebf * rowinv (pure stream) ----------------
__global__ __launch_bounds__(256) void attn_norm(
    const unsigned short* __restrict__ Ebf, const float* __restrict__ rowinvG,
    float* __restrict__ attnp) {
    const size_t total = (size_t)BH * SQ * SQ / 8;   // us8 chunks
    size_t i = (size_t)blockIdx.x * blockDim.x + threadIdx.x;
    size_t stride = (size_t)gridDim.x * blockDim.x;
    for (; i < total; i += stride) {
        us8 e = *(const us8*)(Ebf + i * 8);
        float inv = rowinvG[i >> 8];     // 256 chunks per row
        float4 o0, o1;
        o0.x = bf2f((unsigned short)e[0]) * inv;
        o0.y = bf2f((unsigned short)e[1]) * inv;
        o0.z = bf2f((unsigned short)e[2]) * inv;
        o0.w = bf2f((unsigned short)e[3]) * inv;
        o1.x = bf2f((unsigned short)e[4]) * inv;
        o1.y = bf2f((unsigned short)e[5]) * inv;
        o1.z = bf2f((unsigned short)e[6]) * inv;
        o1.w = bf2f((unsigned short)e[7]) * inv;
        float4* dst = (float4*)(attnp + i * 8);
        dst[0] = o0; dst[1] = o1;
    }
}

// ---------------- fallback path (ws too small for Ebf): R1 f32-E kernels ----------------
__global__ __launch_bounds__(512, 4) void attn_scores_f32(
    const unsigned short* __restrict__ Qb, const unsigned short* __restrict__ Kb,
    const unsigned short* __restrict__ biasT, float* __restrict__ rowinvG,
    float* __restrict__ Ef) {
    __shared__ float rs[32];
    int b = blockIdx.x >> 6, qt = blockIdx.x & 63;
    int q0 = qt * 32;
    int tid = threadIdx.x, lane = tid & 63, w = tid >> 6;
    int l15 = lane & 15, lhi = lane >> 4;
    if (tid < 32) rs[tid] = 0.f;
    __syncthreads();
    size_t headQK = (size_t)b * (SQ * DD);
    size_t ebase = (size_t)b * SQ * SQ;
    bf16x8 qf[2][4];
    #pragma unroll
    for (int qg = 0; qg < 2; ++qg)
        #pragma unroll
        for (int ds = 0; ds < 4; ++ds)
            qf[qg][ds] = *(const bf16x8*)(Qb + headQK +
                           (size_t)(q0 + qg * 16 + l15) * DD + ds * 32 + lhi * 8);
    float ps[2] = {0.f, 0.f};
    #pragma unroll 1
    for (int kt = 0; kt < 16; ++kt) {
        int kbase = w * 256 + kt * 16;
        bf16x8 kf[4];
        #pragma unroll
        for (int ds = 0; ds < 4; ++ds)
            kf[ds] = *(const bf16x8*)(Kb + headQK +
                       (size_t)(kbase + l15) * DD + ds * 32 + lhi * 8);
        #pragma unroll
        for (int qg = 0; qg < 2; ++qg) {
            f32x4 acc = {0.f, 0.f, 0.f, 0.f};
            #pragma unroll
            for (int ds = 0; ds < 4; ++ds)
                acc = __builtin_amdgcn_mfma_f32_16x16x32_bf16(kf[ds], qf[qg][ds], acc, 0, 0, 0);
            int q = q0 + qg * 16 + l15;
            int k = kbase + lhi * 4;
            size_t eidx = ebase + (size_t)q * SQ + k;
            ushort4 bv = *(const ushort4*)(biasT + eidx);
            float u0 = __expf(acc[0] * SCALE + bf2f(bv.x));
            float u1 = __expf(acc[1] * SCALE + bf2f(bv.y));
            float u2 = __expf(acc[2] * SCALE + bf2f(bv.z));
            float u3 = __expf(acc[3] * SCALE + bf2f(bv.w));
            ps[qg] += (u0 + u1) + (u2 + u3);
            float4 st = {u0, u1, u2, u3};
            *(float4*)(Ef + eidx) = st;
        }
    }
    #pragma unroll
    for (int qg = 0; qg < 2; ++qg) {
        float v = ps[qg];
        v += __shfl_xor(v, 16);
        v += __shfl_xor(v, 32);
        if (lane < 16) atomicAdd(&rs[qg * 16 + l15], v);
    }
    __syncthreads();
    if (tid < 32) rowinvG[(size_t)b * SQ + q0 + tid] = 1.0f / rs[tid];
}

__global__ __launch_bounds__(512, 4) void attn_pv_f32(
    const unsigned short* __restrict__ VT, const float* __restrict__ rowinvG,
    float* __restrict__ Ef, float* __restrict__ outp, float* __restrict__ attnp) {
    int b = blockIdx.x >> 6, qt = blockIdx.x & 63;
    int q0 = qt * 32;
    int tid = threadIdx.x, lane = tid & 63, w = tid >> 6;
    int qg = w >> 2, ds = w & 3;
    int l15 = lane & 15, lhi = lane >> 4;
    size_t ebase = (size_t)b * SQ * SQ;
    size_t vbase = (size_t)b * (DD * SQ);
    f32x4 acc[2] = {{0.f,0.f,0.f,0.f},{0.f,0.f,0.f,0.f}};
    const size_t arow = ebase + (size_t)(q0 + qg * 16 + l15) * SQ;
    #pragma unroll 2
    for (int kt = 0; kt < 64; ++kt) {
        int k = kt * 32 + lhi * 8;
        float4 a0 = *(const float4*)(Ef + arow + k);
        float4 a1 = *(const float4*)(Ef + arow + k + 4);
        bf16x8 af;
        af[0] = (short)f2bf(a0.x); af[1] = (short)f2bf(a0.y);
        af[2] = (short)f2bf(a0.z); af[3] = (short)f2bf(a0.w);
        af[4] = (short)f2bf(a1.x); af[5] = (short)f2bf(a1.y);
        af[6] = (short)f2bf(a1.z); af[7] = (short)f2bf(a1.w);
        #pragma unroll
        for (int m = 0; m < 2; ++m) {
            bf16x8 bfr = *(const bf16x8*)(VT + vbase +
                           (size_t)(ds * 32 + m * 16 + l15) * SQ + k);
            acc[m] = __builtin_amdgcn_mfma_f32_16x16x32_bf16(af, bfr, acc[m], 0, 0, 0);
        }
    }
    #pragma unroll
    for (int m = 0; m < 2; ++m)
        #pragma unroll
        for (int r = 0; r < 4; ++r) {
            int q = q0 + qg * 16 + lhi * 4 + r;
            float inv = rowinvG[(size_t)b * SQ + q];
            outp[((size_t)b * SQ + q) * DD + ds * 32 + m * 16 + l15] = acc[m][r] * inv;
        }
    __syncthreads();
    int row = tid >> 4;
    int coff = (tid & 15) * 4;
    float inv = rowinvG[(size_t)b * SQ + q0 + row];
    size_t rbase = ebase + (size_t)(q0 + row) * SQ;
    #pragma unroll 4
    for (int it = 0; it < 32; ++it) {
        int k = it * 64 + coff;
        float4 u = *(const float4*)(Ef + rbase + k);
        u.x *= inv; u.y *= inv; u.z *= inv; u.w *= inv;
        *(float4*)(attnp + rbase + k) = u;
    }
}

// ---------------- naive last-resort ----------------
__global__ void attn_naive(const float* __restrict__ Q, const float* __restrict__ K,
                           const float* __restrict__ V, const float* __restrict__ bias,
                           const void* __restrict__ mask,
                           float* __restrict__ outp, float* __restrict__ attnp) {
    __shared__ float qrow[DD];
    __shared__ float prow[SQ];
    __shared__ float red[4];
    int b = blockIdx.x >> 11;
    int q = blockIdx.x & 2047;
    int tid = threadIdx.x;
    int mshift = mask_byte_shift(mask);
    const unsigned char* M = (const unsigned char*)mask;
    if (tid < DD) qrow[tid] = Q[((size_t)b * SQ + q) * DD + tid];
    __syncthreads();
    float lsum = 0.f;
    for (int k = tid; k < SQ; k += 256) {
        float s = 0.f;
        const float* kr = K + ((size_t)b * SQ + k) * DD;
        for (int d = 0; d < DD; ++d) s += qrow[d] * kr[d];
        s = s * SCALE + bias[((size_t)q * SQ + k) * BH + b];
        size_t midx = ((size_t)b * SQ + q) * SQ + k;
        float p = (M[midx << mshift] != 0) ? 0.f : __expf(s);
        prow[k] = p; lsum += p;
    }
    lsum += __shfl_xor(lsum, 1);  lsum += __shfl_xor(lsum, 2);
    lsum += __shfl_xor(lsum, 4);  lsum += __shfl_xor(lsum, 8);
    lsum += __shfl_xor(lsum, 16); lsum += __shfl_xor(lsum, 32);
    if ((tid & 63) == 0) red[tid >> 6] = lsum;
    __syncthreads();
    float inv = 1.0f / (red[0] + red[1] + red[2] + red[3]);
    for (int k = tid; k < SQ; k += 256) {
        float p = prow[k] * inv;
        prow[k] = p;
        attnp[((size_t)b * SQ + q) * SQ + k] = p;
    }
    __syncthreads();
    if (tid < DD) {
        float o = 0.f;
        for (int k = 0; k < SQ; ++k) o += prow[k] * V[((size_t)b * SQ + k) * DD + tid];
        outp[((size_t)b * SQ + q) * DD + tid] = o;
    }
}

extern "C" void kernel_launch(void* const* d_in, const int* in_sizes, int n_in,
                              void* d_out, int out_size, void* d_ws, size_t ws_size,
                              hipStream_t stream) {
    const float* Q = (const float*)d_in[0];
    const float* K = (const float*)d_in[1];
    const float* V = (const float*)d_in[2];
    const float* bias = (const float*)d_in[3];
    const void* mask = d_in[4];
    float* outp = (float*)d_out;
    float* attnp = outp + (size_t)BH * SQ * DD;

    const size_t tsz = (size_t)BH * SQ * DD;          // 8388608
    const size_t biasN = (size_t)BH * SQ * SQ;        // 134217728
    const size_t cvtB = tsz * 2 * 3;                  // 48 MB
    const size_t needF32 = cvtB + biasN * 2 + (size_t)BH * SQ * 4;   // ~319 MB
    const size_t needBF = needF32 + biasN * 2;                        // ~587 MB

    if (ws_size >= cvtB) {
        char* p = (char*)d_ws;
        unsigned short* Qbf = (unsigned short*)p;          p += tsz * 2;
        unsigned short* Kbf = (unsigned short*)p;          p += tsz * 2;
        unsigned short* VTp = (unsigned short*)p;          p += tsz * 2;
        cvt_qk<<<4096, 256, 0, stream>>>(Q, K, Qbf, Kbf);
        cvt_vt<<<512, 512, 0, stream>>>(V, VTp);
        if (ws_size >= needBF) {
            unsigned short* biasT = (unsigned short*)p;    p += biasN * 2;
            float* rowinvG = (float*)p;                    p += (size_t)BH * SQ * 4;
            unsigned short* Ebf = (unsigned short*)p;
            xform_bias<<<8192, 256, 0, stream>>>(bias, mask, biasT);
            hipFuncSetAttribute((const void*)attn_scores,
                                hipFuncAttributeMaxDynamicSharedMemorySize, 65536);
            hipFuncSetAttribute((const void*)attn_pv,
                                hipFuncAttributeMaxDynamicSharedMemorySize, 65536);
            attn_scores<<<2048, 512, 65536, stream>>>(Qbf, Kbf, biasT, rowinvG, Ebf);
            attn_pv<<<512, 512, 65536, stream>>>(Ebf, VTp, rowinvG, outp);
            attn_norm<<<2048, 256, 0, stream>>>(Ebf, rowinvG, attnp);
        } else if (ws_size >= needF32) {
            unsigned short* biasT = (unsigned short*)p;    p += biasN * 2;
            float* rowinvG = (float*)p;                    p += (size_t)BH * SQ * 4;
            xform_bias<<<8192, 256, 0, stream>>>(bias, mask, biasT);
            attn_scores_f32<<<2048, 512, 0, stream>>>(Qbf, Kbf, biasT, rowinvG, attnp);
            attn_pv_f32<<<2048, 512, 0, stream>>>(VTp, rowinvG, attnp, outp, attnp);
        } else {
            attn_naive<<<BH * SQ, 256, 0, stream>>>(Q, K, V, bias, mask, outp, attnp);
        }
    } else {
        attn_naive<<<BH * SQ, 256, 0, stream>>>(Q, K, V, bias, mask, outp, attnp);
    }
}

// Round 4
// 771.958 us; speedup vs baseline: 2.6427x; 1.0143x over previous
//
#include <hip/hip_runtime.h>
#include <hip/hip_bf16.h>

#define BH 32
#define SQ 2048
#define DD 128
#define SCALE 0.08838834764831845f

typedef short bf16x8 __attribute__((ext_vector_type(8)));
typedef unsigned short us8 __attribute__((ext_vector_type(8)));
typedef float f32x4 __attribute__((ext_vector_type(4)));

typedef __attribute__((address_space(1))) const unsigned gu32;
typedef __attribute__((address_space(3))) unsigned lu32;
__device__ __forceinline__ void gll16(const void* g, void* l) {
    __builtin_amdgcn_global_load_lds((gu32*)g, (lu32*)l, 16, 0, 0);
}

__device__ __forceinline__ unsigned short f2bf(float f) {
    unsigned u = __float_as_uint(f);
    u = u + 0x7FFFu + ((u >> 16) & 1u);   // RNE
    return (unsigned short)(u >> 16);
}
__device__ __forceinline__ float bf2f(unsigned short h) {
    return __uint_as_float(((unsigned)h) << 16);
}

// mask elem width detect: int32 {0,1} has zero bytes at off%4!=0
__device__ __forceinline__ int mask_byte_shift(const void* m) {
    const unsigned char* p = (const unsigned char*)m;
    int l = threadIdx.x & 63;
    unsigned char v = p[l];
    unsigned long long nz = __ballot(((l & 3) != 0) && (v != 0));
    return (nz != 0ull) ? 0 : 2;
}

// ---------------- pre-pass: Q,K f32 -> bf16 ----------------
__global__ void cvt_qk(const float* __restrict__ q, const float* __restrict__ k,
                       unsigned short* __restrict__ qb, unsigned short* __restrict__ kb) {
    const size_t n4 = (size_t)BH * SQ * DD / 4;
    size_t i = (size_t)blockIdx.x * blockDim.x + threadIdx.x;
    size_t stride = (size_t)gridDim.x * blockDim.x;
    for (; i < 2 * n4; i += stride) {
        const float4* src = (i < n4) ? (const float4*)q : (const float4*)k;
        unsigned short* dst = (i < n4) ? qb : kb;
        size_t j = (i < n4) ? i : i - n4;
        float4 v = src[j];
        ushort4 o;
        o.x = f2bf(v.x); o.y = f2bf(v.y); o.z = f2bf(v.z); o.w = f2bf(v.w);
        *(ushort4*)(dst + j * 4) = o;
    }
}

// ---------------- pre-pass: V -> V^T bf16 (VT[b][d][k]) ----------------
#define VT_LD 136
__global__ void cvt_vt(const float* __restrict__ v, unsigned short* __restrict__ vt) {
    __shared__ unsigned short tile[128 * VT_LD];
    int b = blockIdx.x >> 4;
    int kt = blockIdx.x & 15;
    size_t vbase = ((size_t)b * SQ + (size_t)kt * 128) * DD;
    int t = threadIdx.x;   // 512
    for (int i = 0; i < 8; ++i) {
        size_t fi = (size_t)i * 2048 + (size_t)t * 4;
        float4 val = *(const float4*)(v + vbase + fi);
        int kk = (int)(fi >> 7);
        int d0 = (int)(fi & 127);
        tile[(d0 + 0) * VT_LD + kk] = f2bf(val.x);
        tile[(d0 + 1) * VT_LD + kk] = f2bf(val.y);
        tile[(d0 + 2) * VT_LD + kk] = f2bf(val.z);
        tile[(d0 + 3) * VT_LD + kk] = f2bf(val.w);
    }
    __syncthreads();
    int d = t >> 2, ks = (t & 3) * 32;
    size_t obase = (size_t)b * (DD * SQ) + (size_t)d * SQ + (size_t)kt * 128 + ks;
    const unsigned short* row = tile + d * VT_LD + ks;
    #pragma unroll
    for (int j = 0; j < 4; ++j)
        *(int4*)(vt + obase + j * 8) = *(const int4*)(row + j * 8);
}

// ---------------- pre-pass: biasT[b][q][k] = mask ? -1e18 : bias (bf16) ----------------
__global__ void xform_bias(const float* __restrict__ bias, const void* __restrict__ mask,
                           unsigned short* __restrict__ biasT) {
    __shared__ unsigned short T[32][520];
    int q = blockIdx.x >> 2, kc = blockIdx.x & 3;
    int k0 = kc * 512;
    int t = threadIdx.x;   // 256
    int mshift = mask_byte_shift(mask);
    const float4* src = (const float4*)(bias + ((size_t)q * SQ + k0) * BH);
    #pragma unroll
    for (int i = 0; i < 16; ++i) {
        int e4 = i * 256 + t;
        float4 v = src[e4];
        int elem = e4 * 4;
        int k = elem >> 5, b0 = elem & 31;
        T[b0 + 0][k] = f2bf(v.x); T[b0 + 1][k] = f2bf(v.y);
        T[b0 + 2][k] = f2bf(v.z); T[b0 + 3][k] = f2bf(v.w);
    }
    __syncthreads();
    const unsigned short NEGB = f2bf(-1e18f);
    int b = t >> 3;
    int toff = (t & 7) * 8;
    #pragma unroll
    for (int j = 0; j < 8; ++j) {
        int ks = j * 64 + toff;
        size_t gidx = ((size_t)b * SQ + q) * SQ + k0 + ks;
        unsigned short o[8];
        if (mshift == 2) {
            const int4* mp = (const int4*)((const int*)mask + gidx);
            int4 m0 = mp[0], m1 = mp[1];
            o[0] = m0.x ? NEGB : T[b][ks + 0];
            o[1] = m0.y ? NEGB : T[b][ks + 1];
            o[2] = m0.z ? NEGB : T[b][ks + 2];
            o[3] = m0.w ? NEGB : T[b][ks + 3];
            o[4] = m1.x ? NEGB : T[b][ks + 4];
            o[5] = m1.y ? NEGB : T[b][ks + 5];
            o[6] = m1.z ? NEGB : T[b][ks + 6];
            o[7] = m1.w ? NEGB : T[b][ks + 7];
        } else {
            uint2 mw = *(const uint2*)((const unsigned char*)mask + gidx);
            #pragma unroll
            for (int by = 0; by < 4; ++by) {
                o[by]     = ((mw.x >> (by * 8)) & 0xFF) ? NEGB : T[b][ks + by];
                o[4 + by] = ((mw.y >> (by * 8)) & 0xFF) ? NEGB : T[b][ks + 4 + by];
            }
        }
        us8 pk;
        #pragma unroll
        for (int c = 0; c < 8; ++c) pk[c] = o[c];
        *(us8*)(biasT + gidx) = pk;
    }
}

// ---------------- K_A: E = exp(QK^T*scale + biasT) bf16, rowinv ----------------
// grid 2048. XCD swizzle: xcd=bid&7, head = xcd*4 + (slot>>6), qt = slot&63.
// A=K (M=k), B=Q (N=q). K staged via global_load_lds, double-buffered 2x32KB,
// source pre-swizzled (col ^= (row&7)<<4).
__global__ __launch_bounds__(512, 4) void attn_scores(
    const unsigned short* __restrict__ Qb, const unsigned short* __restrict__ Kb,
    const unsigned short* __restrict__ biasT, float* __restrict__ rowinvG,
    unsigned short* __restrict__ Ebf) {
    extern __shared__ char smem[];   // 2 x 32768
    __shared__ float rs[32];
    int bid = blockIdx.x;
    int xcd = bid & 7, slot = bid >> 3;
    int b = xcd * 4 + (slot >> 6);
    int q0 = (slot & 63) * 32;
    int tid = threadIdx.x, lane = tid & 63, w = tid >> 6;
    int l15 = lane & 15, lhi = lane >> 4;

    const char* Kh = (const char*)(Kb + (size_t)b * SQ * DD);
    size_t qhead = (size_t)b * SQ * DD;
    size_t ehead = (size_t)b * SQ * SQ;

    if (tid < 32) rs[tid] = 0.f;

    bf16x8 qf[2][4];
    #pragma unroll
    for (int qg = 0; qg < 2; ++qg)
        #pragma unroll
        for (int kk = 0; kk < 4; ++kk)
            qf[qg][kk] = *(const bf16x8*)(Qb + qhead +
                           (size_t)(q0 + qg * 16 + l15) * DD + kk * 32 + lhi * 8);

    int srow = tid >> 4;
    int scolb = (tid & 15) * 16;
    #pragma unroll
    for (int p = 0; p < 4; ++p) {
        int row = p * 32 + srow;
        gll16(Kh + (size_t)row * 256 + (scolb ^ ((row & 7) << 4)),
              smem + p * 8192 + tid * 16);
    }
    __syncthreads();

    float ps[2] = {0.f, 0.f};
    int kr = w * 16 + l15;
    #pragma unroll 1
    for (int s = 0; s < 16; ++s) {
        int cur = s & 1;
        if (s < 15) {
            const char* base = Kh + (size_t)(s + 1) * 128 * 256;
            #pragma unroll
            for (int p = 0; p < 4; ++p) {
                int row = p * 32 + srow;
                gll16(base + (size_t)row * 256 + (scolb ^ ((row & 7) << 4)),
                      smem + (cur ^ 1) * 32768 + p * 8192 + tid * 16);
            }
        }
        int kg = s * 128 + w * 16 + lhi * 4;
        ushort4 bv[2];
        #pragma unroll
        for (int qg = 0; qg < 2; ++qg)
            bv[qg] = *(const ushort4*)(biasT + ehead +
                        (size_t)(q0 + qg * 16 + l15) * SQ + kg);
        bf16x8 akk[4];
        #pragma unroll
        for (int kk = 0; kk < 4; ++kk)
            akk[kk] = *(const bf16x8*)(smem + cur * 32768 + kr * 256 +
                         ((kk * 64 + lhi * 16) ^ ((kr & 7) << 4)));
        #pragma unroll
        for (int qg = 0; qg < 2; ++qg) {
            f32x4 acc = {0.f, 0.f, 0.f, 0.f};
            #pragma unroll
            for (int kk = 0; kk < 4; ++kk)
                acc = __builtin_amdgcn_mfma_f32_16x16x32_bf16(akk[kk], qf[qg][kk], acc, 0, 0, 0);
            float u0 = __expf(acc[0] * SCALE + bf2f(bv[qg].x));
            float u1 = __expf(acc[1] * SCALE + bf2f(bv[qg].y));
            float u2 = __expf(acc[2] * SCALE + bf2f(bv[qg].z));
            float u3 = __expf(acc[3] * SCALE + bf2f(bv[qg].w));
            ps[qg] += (u0 + u1) + (u2 + u3);
            ushort4 st;
            st.x = f2bf(u0); st.y = f2bf(u1); st.z = f2bf(u2); st.w = f2bf(u3);
            *(ushort4*)(Ebf + ehead + (size_t)(q0 + qg * 16 + l15) * SQ + kg) = st;
        }
        __syncthreads();
    }
    #pragma unroll
    for (int qg = 0; qg < 2; ++qg) {
        float v = ps[qg];
        v += __shfl_xor(v, 16);
        v += __shfl_xor(v, 32);
        if (lane < 16) atomicAdd(&rs[qg * 16 + l15], v);
    }
    __syncthreads();
    if (tid < 32) rowinvG[(size_t)b * SQ + q0 + tid] = 1.0f / rs[tid];
}

// ---------------- K_B: out = (E @ V^T) * rowinv ; attn = E * rowinv ----------------
// grid 512: xcd=bid&7, head = xcd*4 + (slot>>4), qt = slot&15 (128 q rows).
// BK=64; A=E[128x64], B=VT[128x64] staged 16KB each, double-buffered (64KB).
// attn written from the staged A tile (LDS) each kt step -> no separate norm pass.
__global__ __launch_bounds__(512, 4) void attn_pv(
    const unsigned short* __restrict__ Ebf, const unsigned short* __restrict__ VT,
    const float* __restrict__ rowinvG, float* __restrict__ outp,
    float* __restrict__ attnp) {
    extern __shared__ char smem[];   // 2 x (16384 A + 16384 B)
    int bid = blockIdx.x;
    int xcd = bid & 7, slot = bid >> 3;
    int b = xcd * 4 + (slot >> 4);
    int q0 = (slot & 15) * 128;
    int tid = threadIdx.x, lane = tid & 63, w = tid >> 6;
    int wm = w >> 2, wn = w & 3;
    int l15 = lane & 15, lhi = lane >> 4;

    const char* Eh = (const char*)Ebf + ((size_t)b * SQ + q0) * SQ * 2;
    const char* Vh = (const char*)VT + (size_t)b * DD * SQ * 2;

    int srow = tid >> 3;                 // 0..63, +64 per pass
    int scolb = (tid & 7) * 16;          // 0..112

    // normalize-write assignment: thread owns q-row (tid>>2), 16-k chunk (tid&3)*16
    int nrow = tid >> 2;
    int nk = (tid & 3) * 16;
    float ninv = rowinvG[(size_t)b * SQ + q0 + nrow];
    float* nattn = attnp + ((size_t)b * SQ + q0 + nrow) * SQ + nk;

    // prologue stage kt=0
    #pragma unroll
    for (int p = 0; p < 2; ++p) {
        int row = p * 64 + srow;
        int sw = scolb ^ ((row & 7) << 4);
        gll16(Eh + (size_t)row * 4096 + sw, smem + p * 8192 + tid * 16);
        gll16(Vh + (size_t)row * 4096 + sw, smem + 16384 + p * 8192 + tid * 16);
    }
    __syncthreads();

    f32x4 acc[4][2] = {};
    #pragma unroll 1
    for (int kt = 0; kt < 32; ++kt) {
        int cur = kt & 1;
        if (kt < 31) {
            size_t koff = (size_t)(kt + 1) * 128;
            char* dst = smem + (cur ^ 1) * 32768;
            #pragma unroll
            for (int p = 0; p < 2; ++p) {
                int row = p * 64 + srow;
                int sw = scolb ^ ((row & 7) << 4);
                gll16(Eh + (size_t)row * 4096 + koff + sw, dst + p * 8192 + tid * 16);
                gll16(Vh + (size_t)row * 4096 + koff + sw, dst + 16384 + p * 8192 + tid * 16);
            }
        }
        const char* Ab = smem + cur * 32768;
        const char* Bb = Ab + 16384;
        bf16x8 af[4][2], bf[2][2];
        #pragma unroll
        for (int m = 0; m < 4; ++m) {
            int qr = wm * 64 + m * 16 + l15;
            #pragma unroll
            for (int ks = 0; ks < 2; ++ks)
                af[m][ks] = *(const bf16x8*)(Ab + qr * 128 +
                              ((ks * 64 + lhi * 16) ^ ((qr & 7) << 4)));
        }
        #pragma unroll
        for (int n = 0; n < 2; ++n) {
            int dr = wn * 32 + n * 16 + l15;
            #pragma unroll
            for (int ks = 0; ks < 2; ++ks)
                bf[n][ks] = *(const bf16x8*)(Bb + dr * 128 +
                              ((ks * 64 + lhi * 16) ^ ((dr & 7) << 4)));
        }
        #pragma unroll
        for (int m = 0; m < 4; ++m)
            #pragma unroll
            for (int n = 0; n < 2; ++n)
                #pragma unroll
                for (int ks = 0; ks < 2; ++ks)
                    acc[m][n] = __builtin_amdgcn_mfma_f32_16x16x32_bf16(
                                  af[m][ks], bf[n][ks], acc[m][n], 0, 0, 0);
        // attn = E * rowinv, straight from the staged A tile
        {
            const char* Arow = Ab + nrow * 128;
            float* dstf = nattn + (size_t)kt * 64;
            #pragma unroll
            for (int c = 0; c < 2; ++c) {
                int off = ((nk + c * 8) * 2) ^ ((nrow & 7) << 4);
                us8 e = *(const us8*)(Arow + off);
                float4 o0, o1;
                o0.x = bf2f((unsigned short)e[0]) * ninv;
                o0.y = bf2f((unsigned short)e[1]) * ninv;
                o0.z = bf2f((unsigned short)e[2]) * ninv;
                o0.w = bf2f((unsigned short)e[3]) * ninv;
                o1.x = bf2f((unsigned short)e[4]) * ninv;
                o1.y = bf2f((unsigned short)e[5]) * ninv;
                o1.z = bf2f((unsigned short)e[6]) * ninv;
                o1.w = bf2f((unsigned short)e[7]) * ninv;
                *(float4*)(dstf + c * 8) = o0;
                *(float4*)(dstf + c * 8 + 4) = o1;
            }
        }
        __syncthreads();
    }
    #pragma unroll
    for (int m = 0; m < 4; ++m) {
        #pragma unroll
        for (int r = 0; r < 4; ++r) {
            int q = q0 + wm * 64 + m * 16 + lhi * 4 + r;
            float inv = rowinvG[(size_t)b * SQ + q];
            #pragma unroll
            for (int n = 0; n < 2; ++n)
                outp[((size_t)b * SQ + q) * DD + wn * 32 + n * 16 + l15] =
                    acc[m][n][r] * inv;
        }
    }
}

// ---------------- fallback path (ws too small for Ebf): f32-E kernels ----------------
__global__ __launch_bounds__(512, 4) void attn_scores_f32(
    const unsigned short* __restrict__ Qb, const unsigned short* __restrict__ Kb,
    const unsigned short* __restrict__ biasT, float* __restrict__ rowinvG,
    float* __restrict__ Ef) {
    __shared__ float rs[32];
    int b = blockIdx.x >> 6, qt = blockIdx.x & 63;
    int q0 = qt * 32;
    int tid = threadIdx.x, lane = tid & 63, w = tid >> 6;
    int l15 = lane & 15, lhi = lane >> 4;
    if (tid < 32) rs[tid] = 0.f;
    __syncthreads();
    size_t headQK = (size_t)b * (SQ * DD);
    size_t ebase = (size_t)b * SQ * SQ;
    bf16x8 qf[2][4];
    #pragma unroll
    for (int qg = 0; qg < 2; ++qg)
        #pragma unroll
        for (int ds = 0; ds < 4; ++ds)
            qf[qg][ds] = *(const bf16x8*)(Qb + headQK +
                           (size_t)(q0 + qg * 16 + l15) * DD + ds * 32 + lhi * 8);
    float ps[2] = {0.f, 0.f};
    #pragma unroll 1
    for (int kt = 0; kt < 16; ++kt) {
        int kbase = w * 256 + kt * 16;
        bf16x8 kf[4];
        #pragma unroll
        for (int ds = 0; ds < 4; ++ds)
            kf[ds] = *(const bf16x8*)(Kb + headQK +
                       (size_t)(kbase + l15) * DD + ds * 32 + lhi * 8);
        #pragma unroll
        for (int qg = 0; qg < 2; ++qg) {
            f32x4 acc = {0.f, 0.f, 0.f, 0.f};
            #pragma unroll
            for (int ds = 0; ds < 4; ++ds)
                acc = __builtin_amdgcn_mfma_f32_16x16x32_bf16(kf[ds], qf[qg][ds], acc, 0, 0, 0);
            int q = q0 + qg * 16 + l15;
            int k = kbase + lhi * 4;
            size_t eidx = ebase + (size_t)q * SQ + k;
            ushort4 bv = *(const ushort4*)(biasT + eidx);
            float u0 = __expf(acc[0] * SCALE + bf2f(bv.x));
            float u1 = __expf(acc[1] * SCALE + bf2f(bv.y));
            float u2 = __expf(acc[2] * SCALE + bf2f(bv.z));
            float u3 = __expf(acc[3] * SCALE + bf2f(bv.w));
            ps[qg] += (u0 + u1) + (u2 + u3);
            float4 st = {u0, u1, u2, u3};
            *(float4*)(Ef + eidx) = st;
        }
    }
    #pragma unroll
    for (int qg = 0; qg < 2; ++qg) {
        float v = ps[qg];
        v += __shfl_xor(v, 16);
        v += __shfl_xor(v, 32);
        if (lane < 16) atomicAdd(&rs[qg * 16 + l15], v);
    }
    __syncthreads();
    if (tid < 32) rowinvG[(size_t)b * SQ + q0 + tid] = 1.0f / rs[tid];
}

__global__ __launch_bounds__(512, 4) void attn_pv_f32(
    const unsigned short* __restrict__ VT, const float* __restrict__ rowinvG,
    float* __restrict__ Ef, float* __restrict__ outp, float* __restrict__ attnp) {
    int b = blockIdx.x >> 6, qt = blockIdx.x & 63;
    int q0 = qt * 32;
    int tid = threadIdx.x, lane = tid & 63, w = tid >> 6;
    int qg = w >> 2, ds = w & 3;
    int l15 = lane & 15, lhi = lane >> 4;
    size_t ebase = (size_t)b * SQ * SQ;
    size_t vbase = (size_t)b * (DD * SQ);
    f32x4 acc[2] = {{0.f,0.f,0.f,0.f},{0.f,0.f,0.f,0.f}};
    const size_t arow = ebase + (size_t)(q0 + qg * 16 + l15) * SQ;
    #pragma unroll 2
    for (int kt = 0; kt < 64; ++kt) {
        int k = kt * 32 + lhi * 8;
        float4 a0 = *(const float4*)(Ef + arow + k);
        float4 a1 = *(const float4*)(Ef + arow + k + 4);
        bf16x8 af;
        af[0] = (short)f2bf(a0.x); af[1] = (short)f2bf(a0.y);
        af[2] = (short)f2bf(a0.z); af[3] = (short)f2bf(a0.w);
        af[4] = (short)f2bf(a1.x); af[5] = (short)f2bf(a1.y);
        af[6] = (short)f2bf(a1.z); af[7] = (short)f2bf(a1.w);
        #pragma unroll
        for (int m = 0; m < 2; ++m) {
            bf16x8 bfr = *(const bf16x8*)(VT + vbase +
                           (size_t)(ds * 32 + m * 16 + l15) * SQ + k);
            acc[m] = __builtin_amdgcn_mfma_f32_16x16x32_bf16(af, bfr, acc[m], 0, 0, 0);
        }
    }
    #pragma unroll
    for (int m = 0; m < 2; ++m)
        #pragma unroll
        for (int r = 0; r < 4; ++r) {
            int q = q0 + qg * 16 + lhi * 4 + r;
            float inv = rowinvG[(size_t)b * SQ + q];
            outp[((size_t)b * SQ + q) * DD + ds * 32 + m * 16 + l15] = acc[m][r] * inv;
        }
    __syncthreads();
    int row = tid >> 4;
    int coff = (tid & 15) * 4;
    float inv = rowinvG[(size_t)b * SQ + q0 + row];
    size_t rbase = ebase + (size_t)(q0 + row) * SQ;
    #pragma unroll 4
    for (int it = 0; it < 32; ++it) {
        int k = it * 64 + coff;
        float4 u = *(const float4*)(Ef + rbase + k);
        u.x *= inv; u.y *= inv; u.z *= inv; u.w *= inv;
        *(float4*)(attnp + rbase + k) = u;
    }
}

// ---------------- naive last-resort ----------------
__global__ void attn_naive(const float* __restrict__ Q, const float* __restrict__ K,
                           const float* __restrict__ V, const float* __restrict__ bias,
                           const void* __restrict__ mask,
                           float* __restrict__ outp, float* __restrict__ attnp) {
    __shared__ float qrow[DD];
    __shared__ float prow[SQ];
    __shared__ float red[4];
    int b = blockIdx.x >> 11;
    int q = blockIdx.x & 2047;
    int tid = threadIdx.x;
    int mshift = mask_byte_shift(mask);
    const unsigned char* M = (const unsigned char*)mask;
    if (tid < DD) qrow[tid] = Q[((size_t)b * SQ + q) * DD + tid];
    __syncthreads();
    float lsum = 0.f;
    for (int k = tid; k < SQ; k += 256) {
        float s = 0.f;
        const float* kr = K + ((size_t)b * SQ + k) * DD;
        for (int d = 0; d < DD; ++d) s += qrow[d] * kr[d];
        s = s * SCALE + bias[((size_t)q * SQ + k) * BH + b];
        size_t midx = ((size_t)b * SQ + q) * SQ + k;
        float p = (M[midx << mshift] != 0) ? 0.f : __expf(s);
        prow[k] = p; lsum += p;
    }
    lsum += __shfl_xor(lsum, 1);  lsum += __shfl_xor(lsum, 2);
    lsum += __shfl_xor(lsum, 4);  lsum += __shfl_xor(lsum, 8);
    lsum += __shfl_xor(lsum, 16); lsum += __shfl_xor(lsum, 32);
    if ((tid & 63) == 0) red[tid >> 6] = lsum;
    __syncthreads();
    float inv = 1.0f / (red[0] + red[1] + red[2] + red[3]);
    for (int k = tid; k < SQ; k += 256) {
        float p = prow[k] * inv;
        prow[k] = p;
        attnp[((size_t)b * SQ + q) * SQ + k] = p;
    }
    __syncthreads();
    if (tid < DD) {
        float o = 0.f;
        for (int k = 0; k < SQ; ++k) o += prow[k] * V[((size_t)b * SQ + k) * DD + tid];
        outp[((size_t)b * SQ + q) * DD + tid] = o;
    }
}

extern "C" void kernel_launch(void* const* d_in, const int* in_sizes, int n_in,
                              void* d_out, int out_size, void* d_ws, size_t ws_size,
                              hipStream_t stream) {
    const float* Q = (const float*)d_in[0];
    const float* K = (const float*)d_in[1];
    const float* V = (const float*)d_in[2];
    const float* bias = (const float*)d_in[3];
    const void* mask = d_in[4];
    float* outp = (float*)d_out;
    float* attnp = outp + (size_t)BH * SQ * DD;

    const size_t tsz = (size_t)BH * SQ * DD;          // 8388608
    const size_t biasN = (size_t)BH * SQ * SQ;        // 134217728
    const size_t cvtB = tsz * 2 * 3;                  // 48 MB
    const size_t needF32 = cvtB + biasN * 2 + (size_t)BH * SQ * 4;   // ~319 MB
    const size_t needBF = needF32 + biasN * 2;                        // ~587 MB

    if (ws_size >= cvtB) {
        char* p = (char*)d_ws;
        unsigned short* Qbf = (unsigned short*)p;          p += tsz * 2;
        unsigned short* Kbf = (unsigned short*)p;          p += tsz * 2;
        unsigned short* VTp = (unsigned short*)p;          p += tsz * 2;
        cvt_qk<<<4096, 256, 0, stream>>>(Q, K, Qbf, Kbf);
        cvt_vt<<<512, 512, 0, stream>>>(V, VTp);
        if (ws_size >= needBF) {
            unsigned short* biasT = (unsigned short*)p;    p += biasN * 2;
            float* rowinvG = (float*)p;                    p += (size_t)BH * SQ * 4;
            unsigned short* Ebf = (unsigned short*)p;
            xform_bias<<<8192, 256, 0, stream>>>(bias, mask, biasT);
            hipFuncSetAttribute((const void*)attn_scores,
                                hipFuncAttributeMaxDynamicSharedMemorySize, 65536);
            hipFuncSetAttribute((const void*)attn_pv,
                                hipFuncAttributeMaxDynamicSharedMemorySize, 65536);
            attn_scores<<<2048, 512, 65536, stream>>>(Qbf, Kbf, biasT, rowinvG, Ebf);
            attn_pv<<<512, 512, 65536, stream>>>(Ebf, VTp, rowinvG, outp, attnp);
        } else if (ws_size >= needF32) {
            unsigned short* biasT = (unsigned short*)p;    p += biasN * 2;
            float* rowinvG = (float*)p;                    p += (size_t)BH * SQ * 4;
            xform_bias<<<8192, 256, 0, stream>>>(bias, mask, biasT);
            attn_scores_f32<<<2048, 512, 0, stream>>>(Qbf, Kbf, biasT, rowinvG, attnp);
            attn_pv_f32<<<2048, 512, 0, stream>>>(VTp, rowinvG, attnp, outp, attnp);
        } else {
            attn_naive<<<BH * SQ, 256, 0, stream>>>(Q, K, V, bias, mask, outp, attnp);
        }
    } else {
        attn_naive<<<BH * SQ, 256, 0, stream>>>(Q, K, V, bias, mask, outp, attnp);
    }
}